// Round 1
// 10405.470 us; speedup vs baseline: 1.0107x; 1.0107x over previous
//
#include <hip/hip_runtime.h>
#include <hip/hip_bf16.h>
#include <stdint.h>
#include <math.h>

#define BATCH 256
#define SEQ   256
#define EMB   1024
#define HID   1024
#define NCLASS 32000
#define KTOT  2048   // EMB + HID
#define NGATE 8192   // 2 dirs * 4 gates * HID

typedef __attribute__((ext_vector_type(8))) short bf16x8;   // 8 bf16 (4 VGPRs)
typedef __attribute__((ext_vector_type(4))) float f32x4;    // MFMA accumulator

// ---------- scalar helpers ----------
__device__ __forceinline__ unsigned short f2b(float f) {
  union { float f; unsigned u; } v; v.f = f;
  unsigned r = v.u + 0x7FFFu + ((v.u >> 16) & 1u);   // round-to-nearest-even
  return (unsigned short)(r >> 16);
}
__device__ __forceinline__ float b2f(unsigned short s) {
  union { unsigned u; float f; } v; v.u = ((unsigned)s) << 16;
  return v.f;
}
__device__ __forceinline__ void load_lds16(const void* g, void* l) {
  __builtin_amdgcn_global_load_lds(
      (const __attribute__((address_space(1))) unsigned int*)g,
      (__attribute__((address_space(3))) unsigned int*)l, 16, 0, 0);
}
__device__ __forceinline__ float tanh_fast(float x) {
  // 1 - 2/(e^{2x}+1): saturates to +-1, no NaN at large |x|
  return 1.f - 2.f / (__expf(2.f * x) + 1.f);
}

// ---------- embedding lookup + bf16 cast:  Xt[t*B+b][k] = bf16(C[X[b][t]][k]) ----------
__global__ void embed_kernel(const int* __restrict__ X, const float* __restrict__ C,
                             unsigned short* __restrict__ Xt) {
  int n = blockIdx.x;             // n = t*BATCH + b
  int t = n >> 8, b = n & 255;
  int tok = X[(size_t)b * SEQ + t];
  float4 v = ((const float4*)(C + (size_t)tok * EMB))[threadIdx.x];
  ushort4 o;
  o.x = f2b(v.x); o.y = f2b(v.y); o.z = f2b(v.z); o.w = f2b(v.w);
  ((ushort4*)(Xt + (size_t)n * EMB))[threadIdx.x] = o;
}

// ---------- fp32 -> bf16 bulk cast ----------
__global__ void castf_kernel(const float* __restrict__ src, unsigned short* __restrict__ dst,
                             int n4) {
  int i = blockIdx.x * blockDim.x + threadIdx.x;
  if (i < n4) {
    float4 v = ((const float4*)src)[i];
    ushort4 o;
    o.x = f2b(v.x); o.y = f2b(v.y); o.z = f2b(v.z); o.w = f2b(v.w);
    ((ushort4*)dst)[i] = o;
  }
}

// ---------- concatenated bias vector bcat[n], n = d*4096 + gate*1024 + j ----------
__global__ void bcat_kernel(const float* b0, const float* b1, const float* b2,
                            const float* b3, const float* b4, const float* b5,
                            const float* b6, const float* b7, float* __restrict__ bcat) {
  int n = blockIdx.x * 256 + threadIdx.x;     // 8192
  const float* bp[8] = {b0, b1, b2, b3, b4, b5, b6, b7};
  bcat[n] = bp[n >> 10][n & 1023];
}

// ---------- Gx GEMM: gates_x = Xt . Wcat[:,0:1024]^T + bcat, bf16 ----------
// M=65536 (t*B+b), N=8192, K=1024. 128x128 tile, BK=64, 4 waves 2x2.
// Output layout Gx2[t][dir][ug][b][g*16+u]  (ug = unit-group of 16, u = unit in group)
// so each persistent-LSTM block reads one contiguous 128B line per batch row.
__launch_bounds__(256)
__global__ void gx_gemm_kernel(const unsigned short* __restrict__ A,    // [65536][1024]
                               const unsigned short* __restrict__ Bw,   // Wcat [8192][2048]
                               const float* __restrict__ bcat,
                               unsigned short* __restrict__ Gx2) {
  __shared__ unsigned short As[2][128][64];
  __shared__ unsigned short Bs[2][128][64];
  int bid = blockIdx.x;                 // 512 Mtiles x 64 Ntiles, n inner
  int m0 = (bid >> 6) * 128;
  int n0 = (bid & 63) * 128;
  int tid = threadIdx.x;

  auto stage = [&](int buf, int kb) {
    int kbase = kb * 64;
#pragma unroll
    for (int ri = 0; ri < 4; ++ri) {
      int slot = ri * 256 + tid;
      int row = slot >> 3;
      int ce  = (slot & 7) * 8;
      load_lds16(A + (size_t)(m0 + row) * EMB + kbase + ce, &As[buf][row][ce]);
    }
#pragma unroll
    for (int ri = 0; ri < 4; ++ri) {
      int slot = ri * 256 + tid;
      int row = slot >> 3;
      int ce  = (slot & 7) * 8;
      load_lds16(Bw + (size_t)(n0 + row) * KTOT + kbase + ce, &Bs[buf][row][ce]);
    }
  };

  int w = tid >> 6, lane = tid & 63;
  int lm = lane & 15, lq = lane >> 4;
  int wm = w & 1, wn = w >> 1;

  f32x4 zero = {0.f, 0.f, 0.f, 0.f};
  f32x4 acc[4][4];
#pragma unroll
  for (int mi = 0; mi < 4; ++mi)
#pragma unroll
    for (int ni = 0; ni < 4; ++ni) acc[mi][ni] = zero;

  stage(0, 0);
  for (int kb = 0; kb < 16; ++kb) {
    int cur = kb & 1;
    __syncthreads();
    if (kb + 1 < 16) stage(1 - cur, kb + 1);
#pragma unroll
    for (int kc = 0; kc < 2; ++kc) {
      bf16x8 af[4];
#pragma unroll
      for (int mi = 0; mi < 4; ++mi)
        af[mi] = *(const bf16x8*)&As[cur][wm * 64 + mi * 16 + lm][kc * 32 + lq * 8];
#pragma unroll
      for (int ni = 0; ni < 4; ++ni) {
        bf16x8 bb = *(const bf16x8*)&Bs[cur][wn * 64 + ni * 16 + lm][kc * 32 + lq * 8];
#pragma unroll
        for (int mi = 0; mi < 4; ++mi)
          acc[mi][ni] = __builtin_amdgcn_mfma_f32_16x16x32_bf16(af[mi], bb, acc[mi][ni], 0, 0, 0);
      }
    }
  }

  int tt  = m0 >> 8;        // block-constant time index (128-row tile never crosses t)
  int mhb = m0 & 255;       // 0 or 128: which batch half
#pragma unroll
  for (int ni = 0; ni < 4; ++ni) {
    int n  = n0 + wn * 64 + ni * 16 + lm;
    float bn = bcat[n];
    int nb  = n0 + wn * 64 + ni * 16;   // multiple of 16
    int d   = nb >> 12;
    int g   = (nb >> 10) & 3;
    int ugx = (nb >> 4) & 63;
    unsigned short* gdst = Gx2 +
        (((size_t)(tt * 2 + d) * 64 + ugx) * 256) * 64 + g * 16 + lm;
#pragma unroll
    for (int mi = 0; mi < 4; ++mi) {
#pragma unroll
      for (int reg = 0; reg < 4; ++reg) {
        int bloc = mhb + wm * 64 + mi * 16 + lq * 4 + reg;
        gdst[(size_t)bloc * 64] = f2b(acc[mi][ni][reg] + bn);
      }
    }
  }
}

// ---------- persistent bidirectional LSTM recurrence ----------
// 256 blocks (1/CU), each owns (dir, batch-half of 128, 16 hidden units).
// Weights (h-part, 64 rows x 1024) resident in swizzled LDS for all 256 steps.
// c-state in registers. 4 independent 64-block barrier groups (dir x mhalf).
__launch_bounds__(256, 1)
__global__ void lstm_persist(const unsigned short* __restrict__ Wcat,
                             const unsigned short* __restrict__ Gx2,
                             unsigned short* __restrict__ hb0,
                             unsigned short* __restrict__ hb1,
                             unsigned int* __restrict__ bar) {
  __shared__ unsigned short Wlds[64 * 1024];   // 128 KB, rows of 2048B, XOR-swizzled
  __shared__ unsigned short As[2][4096];       // 2 x 8 KB, rows of 64B, XOR-swizzled

  const int bid = blockIdx.x;
  const int dir = bid >> 7;
  const int mh  = (bid >> 6) & 1;
  const int ug  = bid & 63;
  const int j0  = ug * 16;
  const int grp = bid >> 6;          // 0..3  (dir*2 + mh)
  const int tid = threadIdx.x;
  const int w   = tid >> 6;
  const int lane = tid & 63;
  const int lm = lane & 15, lq = lane >> 4;

  const unsigned short* Wd = Wcat + (size_t)dir * 4 * HID * KTOT;

  // ---- one-time weight preload into swizzled LDS ----
  // physical byte P in row n: logical in-row offset = (P&2047) ^ ((n&7)<<4)
#pragma unroll
  for (int i = 0; i < 32; ++i) {
    int s = i * 256 + tid;            // 16B slot 0..8191 (dest linear in lane)
    int P = s << 4;
    int n = P >> 11;                  // LDS row 0..63  (= g*16 + u)
    int offl = (P & 2047) ^ ((n & 7) << 4);
    int g = n >> 4, u = n & 15;
    load_lds16(Wd + (size_t)(g * HID + j0 + u) * KTOT + EMB + (offl >> 1),
               Wlds + (P >> 1));
  }

  // ---- A-staging slot precompute: invert P = L ^ ((row&7)<<4), row = L>>6 ----
  int sp0 = 0, sp1 = 0, lp0 = 0, lp1 = 0;
#pragma unroll
  for (int r = 0; r < 2; ++r) {
    int s = r * 256 + tid;            // 0..511
    int P = s << 4;                   // 0..8191
    int r2 = (P >> 8) & 1;
    int r1 = (P >> 7) & 1;
    int r0 = ((P >> 6) & 1) ^ r2;
    int L  = P ^ ((r0 | (r1 << 1) | (r2 << 2)) << 4);
    int row  = L >> 6;                // 0..127
    int colb = L & 63;                // byte within 32-elem k-chunk
    if (r == 0) { sp0 = row * HID + (colb >> 1); lp0 = P >> 1; }
    else        { sp1 = row * HID + (colb >> 1); lp1 = P >> 1; }
  }

  // ---- hoisted LDS read offsets (swizzled) ----
  int row0 = w * 32 + lm;             // wave owns rows [w*32, w*32+32)
  int row1 = row0 + 16;
  int aP0 = ((row0 * 64 + lq * 16) ^ ((row0 & 7) << 4)) >> 1;
  int aP1 = ((row1 * 64 + lq * 16) ^ ((row1 & 7) << 4)) >> 1;
  int swzB = (lm & 7) << 4;

  float cs[2][4];
#pragma unroll
  for (int mi = 0; mi < 2; ++mi)
#pragma unroll
    for (int reg = 0; reg < 4; ++reg) cs[mi][reg] = 0.f;

  const int rbb = w * 32 + lq * 4;              // + mi*16 + reg = batch row in half
  const size_t hblk = ((size_t)dir * 256 + mh * 128) * 1024;
  unsigned int tgt = 0;
  unsigned int* barp = bar + grp * 32;          // 128B-spaced counters

  __syncthreads();   // weights resident (barrier drains vmcnt)

  for (int t = 0; t < SEQ; ++t) {
    int td = dir ? (SEQ - 1 - t) : t;
    const unsigned short* hprev = ((t & 1) ? hb1 : hb0) + hblk;
    unsigned short*       hnext = ((t & 1) ? hb0 : hb1) + hblk;

    // ---- Gx prefetch (issue early, consume in epilogue) ----
    const unsigned short* gxt = Gx2 +
        ((((size_t)td * 2 + dir) * 64 + ug) * 256 + mh * 128) * 64 + lm;
    unsigned short gxr[2][4][4];
#pragma unroll
    for (int mi = 0; mi < 2; ++mi)
#pragma unroll
      for (int reg = 0; reg < 4; ++reg) {
        const unsigned short* gp = gxt + (size_t)(rbb + mi * 16 + reg) * 64;
#pragma unroll
        for (int g = 0; g < 4; ++g) gxr[mi][g][reg] = gp[g * 16];
      }

    f32x4 acc[2][4];
#pragma unroll
    for (int mi = 0; mi < 2; ++mi)
#pragma unroll
      for (int g = 0; g < 4; ++g) acc[mi][g] = (f32x4){0.f, 0.f, 0.f, 0.f};

    if (t) {     // t=0: h(-1)=0, gates = Gx only
      load_lds16(hprev + sp0, &As[0][0] + lp0);
      load_lds16(hprev + sp1, &As[0][0] + lp1);
      for (int kb = 0; kb < 32; ++kb) {
        int cur = kb & 1;
        __syncthreads();
        if (kb + 1 < 32) {
          const unsigned short* hsrc = hprev + (kb + 1) * 32;
          load_lds16(hsrc + sp0, &As[1 - cur][0] + lp0);
          load_lds16(hsrc + sp1, &As[1 - cur][0] + lp1);
        }
        bf16x8 a0 = *(const bf16x8*)&As[cur][aP0];
        bf16x8 a1 = *(const bf16x8*)&As[cur][aP1];
        int off = ((kb * 64 + lq * 16) ^ swzB) >> 1;
#pragma unroll
        for (int g = 0; g < 4; ++g) {
          bf16x8 bb = *(const bf16x8*)&Wlds[(g * 16 + lm) * 1024 + off];
          acc[0][g] = __builtin_amdgcn_mfma_f32_16x16x32_bf16(a0, bb, acc[0][g], 0, 0, 0);
          acc[1][g] = __builtin_amdgcn_mfma_f32_16x16x32_bf16(a1, bb, acc[1][g], 0, 0, 0);
        }
      }
    }

    // ---- fused gate epilogue; c stays in registers ----
#pragma unroll
    for (int mi = 0; mi < 2; ++mi) {
#pragma unroll
      for (int reg = 0; reg < 4; ++reg) {
        float pi = acc[mi][0][reg] + b2f(gxr[mi][0][reg]);
        float pf = acc[mi][1][reg] + b2f(gxr[mi][1][reg]);
        float po = acc[mi][2][reg] + b2f(gxr[mi][2][reg]);
        float pg = acc[mi][3][reg] + b2f(gxr[mi][3][reg]);
        float ig = 1.f / (1.f + __expf(-pi));
        float fg = 1.f / (1.f + __expf(-pf));
        float og = 1.f / (1.f + __expf(-po));
        float gg = tanh_fast(pg);
        float cn = fg * cs[mi][reg] + ig * gg;
        cs[mi][reg] = cn;
        int rb = rbb + mi * 16 + reg;
        hnext[(size_t)rb * 1024 + j0 + lm] = f2b(og * tanh_fast(cn));
      }
    }

    // ---- 64-block group barrier (device-scope, monotonic counter) ----
    tgt += 64;
    __syncthreads();                  // drains this block's h stores (vmcnt 0)
    if (tid == 0) {
      __threadfence();                // release: wbl2 -> writes visible cross-XCD
      atomicAdd(barp, 1u);
      while (__hip_atomic_load(barp, __ATOMIC_RELAXED,
                               __HIP_MEMORY_SCOPE_AGENT) < tgt) {}
    }
    __syncthreads();
    __threadfence();                  // acquire: invalidate stale L1/L2 lines
  }
}

// ---------- one LSTM time step, both directions (FALLBACK path only) ----------
#define BM 128
#define BN 64
#define BK 64
__launch_bounds__(256)
__global__ void lstm_step_kernel(const unsigned short* __restrict__ Xt,
                                 const unsigned short* __restrict__ Wcat,
                                 const unsigned short* __restrict__ Gx,   // null in fallback
                                 const unsigned short* __restrict__ h_in,
                                 unsigned short* __restrict__ h_out,
                                 float* __restrict__ c_st,
                                 const float* __restrict__ b0, const float* __restrict__ b1,
                                 const float* __restrict__ b2, const float* __restrict__ b3,
                                 const float* __restrict__ b4, const float* __restrict__ b5,
                                 const float* __restrict__ b6, const float* __restrict__ b7,
                                 int t) {
  __shared__ unsigned short As[2][BM][BK];
  __shared__ unsigned short Bs[2][BN][BK];

  int bid = blockIdx.x;
  int d   = bid >> 7;            // direction
  int r   = bid & 127;
  int m0  = (r & 1) * BM;        // batch-tile base
  int j0  = (r >> 1) * 16;       // hidden-unit tile base
  int td  = d ? (SEQ - 1 - t) : t;
  int tid = threadIdx.x;

  bool useGx = (Gx != nullptr);
  int  kiters = useGx ? (HID / BK) : (KTOT / BK);
  int  koff   = useGx ? EMB : 0;

  const unsigned short* Asrc0 = Xt  + ((size_t)td * BATCH + m0) * EMB;
  const unsigned short* Asrc1 = h_in + ((size_t)d * BATCH + m0) * HID;
  const unsigned short* Wd    = Wcat + (size_t)d * 4 * HID * KTOT;

  auto stageA = [&](int buf, int kb) {
    int kbase = kb * BK;
    const unsigned short* src; int ko;
    if (useGx)            { src = Asrc1; ko = kbase; }
    else if (kbase < EMB) { src = Asrc0; ko = kbase; }
    else                  { src = Asrc1; ko = kbase - EMB; }
#pragma unroll
    for (int ri = 0; ri < 4; ++ri) {
      int slot = ri * 256 + tid;
      int row = slot >> 3;
      int ce  = (slot & 7) * 8;
      load_lds16(src + (size_t)row * 1024 + ko + ce, &As[buf][row][ce]);
    }
  };
  auto stageB = [&](int buf, int kb) {
    int kbase = koff + kb * BK;
#pragma unroll
    for (int ri = 0; ri < 2; ++ri) {
      int slot = ri * 256 + tid;
      int rr  = slot >> 3;
      int g8  = rr >> 4;
      int jj  = rr & 15;
      int ce  = (slot & 7) * 8;
      load_lds16(Wd + (size_t)(g8 * HID + j0 + jj) * KTOT + kbase + ce, &Bs[buf][rr][ce]);
    }
  };

  int w = tid >> 6, lane = tid & 63;
  int lm = lane & 15, lq = lane >> 4;

  f32x4 zero = {0.f, 0.f, 0.f, 0.f};
  f32x4 acc[2][4];
#pragma unroll
  for (int mi = 0; mi < 2; ++mi)
#pragma unroll
    for (int g8 = 0; g8 < 4; ++g8) acc[mi][g8] = zero;

  stageA(0, 0); stageB(0, 0);
  for (int kb = 0; kb < kiters; ++kb) {
    int cur = kb & 1;
    __syncthreads();
    if (kb + 1 < kiters) { stageA(1 - cur, kb + 1); stageB(1 - cur, kb + 1); }
#pragma unroll
    for (int kc = 0; kc < 2; ++kc) {
      bf16x8 a0 = *(const bf16x8*)&As[cur][w * 32 +  0 + lm][kc * 32 + lq * 8];
      bf16x8 a1 = *(const bf16x8*)&As[cur][w * 32 + 16 + lm][kc * 32 + lq * 8];
#pragma unroll
      for (int g8 = 0; g8 < 4; ++g8) {
        bf16x8 bb = *(const bf16x8*)&Bs[cur][g8 * 16 + lm][kc * 32 + lq * 8];
        acc[0][g8] = __builtin_amdgcn_mfma_f32_16x16x32_bf16(a0, bb, acc[0][g8], 0, 0, 0);
        acc[1][g8] = __builtin_amdgcn_mfma_f32_16x16x32_bf16(a1, bb, acc[1][g8], 0, 0, 0);
      }
    }
  }

  const float* bi = d ? b4 : b0;
  const float* bf = d ? b5 : b1;
  const float* bo = d ? b6 : b2;
  const float* bgp= d ? b7 : b3;
  int j = j0 + lm;
  float vbi, vbf, vbo, vbg;
  if (!useGx) { vbi = bi[j]; vbf = bf[j]; vbo = bo[j]; vbg = bgp[j]; }
  else        { vbi = vbf = vbo = vbg = 0.f; }

#pragma unroll
  for (int mi = 0; mi < 2; ++mi) {
#pragma unroll
    for (int reg = 0; reg < 4; ++reg) {
      int b = m0 + w * 32 + mi * 16 + lq * 4 + reg;
      float pi = acc[mi][0][reg] + vbi;
      float pf = acc[mi][1][reg] + vbf;
      float po = acc[mi][2][reg] + vbo;
      float pg = acc[mi][3][reg] + vbg;
      float ig = 1.f / (1.f + __expf(-pi));
      float fg = 1.f / (1.f + __expf(-pf));
      float og = 1.f / (1.f + __expf(-po));
      float gg = tanhf(pg);
      size_t ci = ((size_t)d * BATCH + b) * HID + j;
      float cn = fg * c_st[ci] + ig * gg;
      c_st[ci] = cn;
      h_out[ci] = f2b(og * tanhf(cn));
    }
  }
}

// ---------- hsum = bf16(h1 + h2) ----------
__global__ void hsum_kernel(const unsigned short* __restrict__ hfin,
                            unsigned short* __restrict__ hs) {
  int i = blockIdx.x * 256 + threadIdx.x;
  ushort4 a = ((const ushort4*)hfin)[i];
  ushort4 b = ((const ushort4*)(hfin + (size_t)BATCH * HID))[i];
  ushort4 o;
  o.x = f2b(b2f(a.x) + b2f(b.x));
  o.y = f2b(b2f(a.y) + b2f(b.y));
  o.z = f2b(b2f(a.z) + b2f(b.z));
  o.w = f2b(b2f(a.w) + b2f(b.w));
  ((ushort4*)hs)[i] = o;
}

// ---------- output GEMM: out[b][n] = hsum[b] . Wout[n] + b_out[n] ----------
__launch_bounds__(256)
__global__ void out_gemm_kernel(const unsigned short* __restrict__ A,   // [256][1024]
                                const unsigned short* __restrict__ B,   // [32000][1024]
                                const float* __restrict__ bias,
                                float* __restrict__ Cout) {
  __shared__ unsigned short As[2][128][64];
  __shared__ unsigned short Bs[2][128][64];
  int bid = blockIdx.x;                 // 2 Mtiles x 250 Ntiles
  int m0 = (bid & 1) * 128;
  int n0 = (bid >> 1) * 128;
  int tid = threadIdx.x;

  auto stage = [&](int buf, int kb) {
    int kbase = kb * 64;
#pragma unroll
    for (int ri = 0; ri < 4; ++ri) {
      int slot = ri * 256 + tid;
      int row = slot >> 3;
      int ce  = (slot & 7) * 8;
      load_lds16(A + ((size_t)(m0 + row)) * HID + kbase + ce, &As[buf][row][ce]);
    }
#pragma unroll
    for (int ri = 0; ri < 4; ++ri) {
      int slot = ri * 256 + tid;
      int row = slot >> 3;
      int ce  = (slot & 7) * 8;
      load_lds16(B + ((size_t)(n0 + row)) * HID + kbase + ce, &Bs[buf][row][ce]);
    }
  };

  int w = tid >> 6, lane = tid & 63;
  int lm = lane & 15, lq = lane >> 4;
  int wm = w & 1, wn = w >> 1;

  f32x4 zero = {0.f, 0.f, 0.f, 0.f};
  f32x4 acc[4][4];
#pragma unroll
  for (int mi = 0; mi < 4; ++mi)
#pragma unroll
    for (int ni = 0; ni < 4; ++ni) acc[mi][ni] = zero;

  stage(0, 0);
  for (int kb = 0; kb < 16; ++kb) {
    int cur = kb & 1;
    __syncthreads();
    if (kb + 1 < 16) stage(1 - cur, kb + 1);
#pragma unroll
    for (int kc = 0; kc < 2; ++kc) {
      bf16x8 af[4];
#pragma unroll
      for (int mi = 0; mi < 4; ++mi)
        af[mi] = *(const bf16x8*)&As[cur][wm * 64 + mi * 16 + lm][kc * 32 + lq * 8];
#pragma unroll
      for (int ni = 0; ni < 4; ++ni) {
        bf16x8 bb = *(const bf16x8*)&Bs[cur][wn * 64 + ni * 16 + lm][kc * 32 + lq * 8];
#pragma unroll
        for (int mi = 0; mi < 4; ++mi)
          acc[mi][ni] = __builtin_amdgcn_mfma_f32_16x16x32_bf16(af[mi], bb, acc[mi][ni], 0, 0, 0);
      }
    }
  }

#pragma unroll
  for (int ni = 0; ni < 4; ++ni) {
    int n = n0 + wn * 64 + ni * 16 + lm;
    float bn = bias[n];
#pragma unroll
    for (int mi = 0; mi < 4; ++mi) {
#pragma unroll
      for (int reg = 0; reg < 4; ++reg) {
        int m = m0 + wm * 64 + mi * 16 + lq * 4 + reg;
        Cout[(size_t)m * NCLASS + n] = acc[mi][ni][reg] + bn;
      }
    }
  }
}

// ---------- host launcher ----------
extern "C" void kernel_launch(void* const* d_in, const int* in_sizes, int n_in,
                              void* d_out, int out_size, void* d_ws, size_t ws_size,
                              hipStream_t stream) {
  const int*   X    = (const int*)d_in[0];
  const float* C    = (const float*)d_in[1];
  const float* Wg[8];
  for (int i = 0; i < 8; ++i) Wg[i] = (const float*)d_in[2 + i];
  const float* bg[8];
  for (int i = 0; i < 8; ++i) bg[i] = (const float*)d_in[10 + i];
  const float* Wout = (const float*)d_in[18];
  const float* bout = (const float*)d_in[19];
  float* out = (float*)d_out;

  // workspace carve
  const size_t szXt   = (size_t)SEQ * BATCH * EMB * 2;      // 134.2 MB
  const size_t szWcat = (size_t)8 * HID * KTOT * 2;         //  33.6 MB
  const size_t szWob  = (size_t)NCLASS * HID * 2;           //  65.5 MB
  const size_t szH    = (size_t)2 * BATCH * HID * 2;        //   1  MB
  const size_t szC    = (size_t)2 * BATCH * HID * 4;        //   2  MB
  const size_t szHs   = (size_t)BATCH * HID * 2;            // 0.5 MB
  const size_t szBc   = (size_t)NGATE * 4;                  //  32 KB
  const size_t szGx   = (size_t)SEQ * BATCH * NGATE * 2;    // 1.074 GB

  uint8_t* p = (uint8_t*)d_ws;
  unsigned short* Xt   = (unsigned short*)p; p += szXt;
  unsigned short* Wcat = (unsigned short*)p; p += szWcat;
  unsigned short* Wob  = (unsigned short*)p; p += szWob;
  unsigned short* hb0  = (unsigned short*)p; p += szH;
  unsigned short* hb1  = (unsigned short*)p; p += szH;
  float*          cst  = (float*)p;          p += szC;
  unsigned short* hs   = (unsigned short*)p; p += szHs;
  float*          bcat = (float*)p;          p += szBc;
  unsigned short* Gx   = (unsigned short*)p; p += szGx;

  size_t need_full = (size_t)(p - (uint8_t*)d_ws);
  bool useGx = (ws_size >= need_full);
  if (!useGx) Gx = nullptr;

  hipMemsetAsync(hb0, 0, szH, stream);   // h(-1) = 0 (fallback path)
  hipMemsetAsync(cst, 0, szC, stream);   // c(-1) = 0 (fallback) / barrier counters

  embed_kernel<<<SEQ * BATCH, 256, 0, stream>>>(X, C, Xt);
  for (int i = 0; i < 8; ++i)
    castf_kernel<<<2048, 256, 0, stream>>>(Wg[i], Wcat + (size_t)i * HID * KTOT,
                                           (HID * KTOT) / 4);
  castf_kernel<<<32000, 256, 0, stream>>>(Wout, Wob, (NCLASS * HID) / 4);

  if (useGx) {
    bcat_kernel<<<NGATE / 256, 256, 0, stream>>>(bg[0], bg[1], bg[2], bg[3],
                                                 bg[4], bg[5], bg[6], bg[7], bcat);
    gx_gemm_kernel<<<512 * 64, 256, 0, stream>>>(Xt, Wcat, bcat, Gx);
    // persistent recurrence: one launch for all 256 steps, both directions
    unsigned int* bar = (unsigned int*)cst;    // reuse (cst unused on this path)
    lstm_persist<<<256, 256, 0, stream>>>(Wcat, Gx, hb0, hb1, bar);
  } else {
    unsigned short* hbuf[2] = {hb0, hb1};
    for (int t = 0; t < SEQ; ++t) {
      lstm_step_kernel<<<256, 256, 0, stream>>>(
          Xt, Wcat, Gx, hbuf[t & 1], hbuf[(t + 1) & 1], cst,
          bg[0], bg[1], bg[2], bg[3], bg[4], bg[5], bg[6], bg[7], t);
    }
  }
  // final h is in hb0 after 256 steps
  hsum_kernel<<<256, 256, 0, stream>>>(hb0, hs);
  out_gemm_kernel<<<500, 256, 0, stream>>>(hs, Wob, bout, out);
}